// Round 1
// baseline (341.574 us; speedup 1.0000x reference)
//
#include <hip/hip_runtime.h>
#include <stdint.h>

// Problem shape (fixed by harness): x(4096x2048) @ W(2048x2048) + bias + probs, tanh.
static constexpr int MM = 4096;  // rows of x / out
static constexpr int KK = 2048;  // inner dim (N in reference)
static constexpr int NN = 2048;  // cols of out (M in reference)

typedef float floatx4 __attribute__((ext_vector_type(4)));
typedef __bf16 bf16x8 __attribute__((ext_vector_type(8)));

__device__ __forceinline__ unsigned short bf16_rne(float x) {
  union { float f; uint32_t u; } c; c.f = x;
  uint32_t u = c.u;
  u += 0x7fffu + ((u >> 16) & 1u);   // round-to-nearest-even
  return (unsigned short)(u >> 16);
}
__device__ __forceinline__ float bf16_as_f32(unsigned short h) {
  union { float f; uint32_t u; } c; c.u = ((uint32_t)h) << 16;
  return c.f;
}

// ---------------- Pre-pass 1: split x (f32, MMxKK) -> hi/lo bf16 planes ----
__global__ __launch_bounds__(256) void split_x_kernel(
    const float* __restrict__ in, unsigned short* __restrict__ hi,
    unsigned short* __restrict__ lo, int n4) {
  int idx = blockIdx.x * 256 + threadIdx.x;
  if (idx >= n4) return;
  float4 v = ((const float4*)in)[idx];
  ushort4 h, l;
  float t;
  h.x = bf16_rne(v.x); t = v.x - bf16_as_f32(h.x); l.x = bf16_rne(t);
  h.y = bf16_rne(v.y); t = v.y - bf16_as_f32(h.y); l.y = bf16_rne(t);
  h.z = bf16_rne(v.z); t = v.z - bf16_as_f32(h.z); l.z = bf16_rne(t);
  h.w = bf16_rne(v.w); t = v.w - bf16_as_f32(h.w); l.w = bf16_rne(t);
  ((ushort4*)hi)[idx] = h;
  ((ushort4*)lo)[idx] = l;
}

// ------- Pre-pass 2: transpose+split W (KKxNN f32) -> Bt hi/lo (NNxKK bf16) -
__global__ __launch_bounds__(256) void wsplit_kernel(
    const float* __restrict__ W, unsigned short* __restrict__ bhi,
    unsigned short* __restrict__ blo) {
  __shared__ float tile[32][33];
  const int tx = threadIdx.x;  // 0..31
  const int ty = threadIdx.y;  // 0..7
  const int n0 = blockIdx.x * 32;
  const int k0 = blockIdx.y * 32;
#pragma unroll
  for (int i = 0; i < 4; i++) {
    int k = k0 + ty * 4 + i;
    tile[ty * 4 + i][tx] = W[(size_t)k * NN + n0 + tx];  // coalesced along N
  }
  __syncthreads();
#pragma unroll
  for (int i = 0; i < 4; i++) {
    int n = n0 + ty * 4 + i;
    float v = tile[tx][ty * 4 + i];
    unsigned short h = bf16_rne(v);
    float lof = v - bf16_as_f32(h);
    size_t o = (size_t)n * KK + k0 + tx;  // coalesced along K
    bhi[o] = h;
    blo[o] = bf16_rne(lof);
  }
}

// ------- Pre-pass 3: probs[i] = (1/n) * prod cos^2(E[d,i,t]); fuse bias ----
// state0 is column-uniform and the gate is translation-invariant along axis 1,
// so each gate is just state *= cos(angle): the scan collapses to 27 cosines.
__global__ __launch_bounds__(256) void bias_probs_kernel(
    const float* __restrict__ E, const float* __restrict__ cb,
    float* __restrict__ bias2) {
  int i = blockIdx.x * 256 + threadIdx.x;
  if (i >= NN) return;
  float p = 1.0f / 2048.0f;
#pragma unroll
  for (int d = 0; d < 9; d++) {
    const float* a = E + (size_t)d * (2048 * 2048) + (size_t)i * 2048;
#pragma unroll
    for (int t = 0; t < 3; t++) {
      float c = cosf(a[t]);
      p *= c * c;
    }
  }
  bias2[i] = cb[i] + p;
}

// ---------------- Main GEMM: 3-term bf16 split, fused tanh epilogue --------
// C = Ahi*Bhi + Ahi*Blo + Alo*Bhi ; out = tanh(C + bias2[col])
// 128x128 tile, BK=32, 256 threads (4 waves, 2x2), 4x4 16x16x32 MFMA per wave.
#define GLL(dst, src)                                                        \
  __builtin_amdgcn_global_load_lds(                                          \
      (const __attribute__((address_space(1))) void*)(src),                  \
      (__attribute__((address_space(3))) void*)(dst), 16, 0, 0)

__global__ __launch_bounds__(256, 2) void gemm_tanh_kernel(
    const unsigned short* __restrict__ Ahi, const unsigned short* __restrict__ Alo,
    const unsigned short* __restrict__ Bhi, const unsigned short* __restrict__ Blo,
    const float* __restrict__ bias2, float* __restrict__ out) {
  __shared__ __align__(16) unsigned short sA[2][128 * 32];  // [hi/lo][m][k]
  __shared__ __align__(16) unsigned short sB[2][128 * 32];  // [hi/lo][n][k]

  const int tid = threadIdx.x;
  const int lane = tid & 63;
  const int wave = tid >> 6;
  const int wm = (wave >> 1) * 64;
  const int wn = (wave & 1) * 64;
  const int bm = blockIdx.y * 128;
  const int bn = blockIdx.x * 128;

  // staging: thread t covers row t/4 (and t/4+64), 8-bf16 chunk (t%4)*8
  const int srow = tid >> 2;
  const int scol = (tid & 3) * 8;
  const size_t a_base = (size_t)(bm + srow) * KK + scol;
  const size_t b_base = (size_t)(bn + srow) * KK + scol;
  const int lds_off = tid * 8;  // *2B = lane*16B contiguous per wave

  const int fm = lane & 15;          // A row / B row (n)
  const int fk = (lane >> 4) * 8;    // k chunk

  floatx4 acc[4][4];
#pragma unroll
  for (int i = 0; i < 4; i++)
#pragma unroll
    for (int j = 0; j < 4; j++) acc[i][j] = {0.f, 0.f, 0.f, 0.f};

  for (int k0 = 0; k0 < KK; k0 += 32) {
    GLL(&sA[0][lds_off],        Ahi + a_base + k0);
    GLL(&sA[0][lds_off + 2048], Ahi + a_base + k0 + (size_t)64 * KK);
    GLL(&sA[1][lds_off],        Alo + a_base + k0);
    GLL(&sA[1][lds_off + 2048], Alo + a_base + k0 + (size_t)64 * KK);
    GLL(&sB[0][lds_off],        Bhi + b_base + k0);
    GLL(&sB[0][lds_off + 2048], Bhi + b_base + k0 + (size_t)64 * KK);
    GLL(&sB[1][lds_off],        Blo + b_base + k0);
    GLL(&sB[1][lds_off + 2048], Blo + b_base + k0 + (size_t)64 * KK);
    __syncthreads();  // compiler emits vmcnt(0) drain before barrier

    bf16x8 fa[2][4], fb[2][4];
#pragma unroll
    for (int t = 0; t < 4; t++) {
      int ao = (wm + t * 16 + fm) * 32 + fk;
      fa[0][t] = *(const bf16x8*)(&sA[0][ao]);
      fa[1][t] = *(const bf16x8*)(&sA[1][ao]);
      int bo = (wn + t * 16 + fm) * 32 + fk;
      fb[0][t] = *(const bf16x8*)(&sB[0][bo]);
      fb[1][t] = *(const bf16x8*)(&sB[1][bo]);
    }
#pragma unroll
    for (int i = 0; i < 4; i++)
#pragma unroll
      for (int j = 0; j < 4; j++) {
        acc[i][j] = __builtin_amdgcn_mfma_f32_16x16x32_bf16(fa[0][i], fb[0][j], acc[i][j], 0, 0, 0);
        acc[i][j] = __builtin_amdgcn_mfma_f32_16x16x32_bf16(fa[0][i], fb[1][j], acc[i][j], 0, 0, 0);
        acc[i][j] = __builtin_amdgcn_mfma_f32_16x16x32_bf16(fa[1][i], fb[0][j], acc[i][j], 0, 0, 0);
      }
    __syncthreads();
  }

  // epilogue: C/D layout col=lane&15, row=(lane>>4)*4+reg  [m89/m91-verified]
  const int cr = (lane >> 4) * 4;
  const int cc = lane & 15;
#pragma unroll
  for (int j = 0; j < 4; j++) {
    int col = bn + wn + j * 16 + cc;
    float b2 = bias2[col];
#pragma unroll
    for (int i = 0; i < 4; i++) {
      int row0 = bm + wm + i * 16 + cr;
      floatx4 a = acc[i][j];
#pragma unroll
      for (int r = 0; r < 4; r++) {
        out[(size_t)(row0 + r) * NN + col] = tanhf(a[r] + b2);
      }
    }
  }
}

// ---------------- Fallback (only if ws_size is too small): naive fp32 ------
__global__ __launch_bounds__(256) void fallback_gemm(
    const float* __restrict__ x, const float* __restrict__ E,
    const float* __restrict__ W, const float* __restrict__ cb,
    float* __restrict__ out) {
  __shared__ float sA[16][16];
  __shared__ float sB[16][17];
  __shared__ float sbias[16];
  const int tx = threadIdx.x, ty = threadIdx.y;
  const int row = blockIdx.y * 16 + ty;
  const int col = blockIdx.x * 16 + tx;
  if (ty == 0) {
    float p = 1.0f / 2048.0f;
    for (int d = 0; d < 9; d++) {
      const float* a = E + (size_t)d * (2048 * 2048) + (size_t)col * 2048;
      for (int t = 0; t < 3; t++) { float c = cosf(a[t]); p *= c * c; }
    }
    sbias[tx] = p + cb[col];
  }
  float acc = 0.f;
  for (int k0 = 0; k0 < KK; k0 += 16) {
    __syncthreads();
    sA[ty][tx] = x[(size_t)row * KK + k0 + tx];
    sB[ty][tx] = W[(size_t)(k0 + ty) * NN + col];
    __syncthreads();
#pragma unroll
    for (int kk = 0; kk < 16; kk++) acc += sA[ty][kk] * sB[kk][tx];
  }
  out[(size_t)row * NN + col] = tanhf(acc + sbias[tx]);
}

extern "C" void kernel_launch(void* const* d_in, const int* in_sizes, int n_in,
                              void* d_out, int out_size, void* d_ws, size_t ws_size,
                              hipStream_t stream) {
  const float* x  = (const float*)d_in[0];
  const float* E  = (const float*)d_in[1];  // eternal_weights (9,2048,2048)
  // d_in[2] = eternal_biases: unused by the reference
  const float* W  = (const float*)d_in[3];  // classical_weights (2048,2048)
  const float* cb = (const float*)d_in[4];  // classical_biases (2048,)
  float* out = (float*)d_out;

  const size_t MB = 1024 * 1024;
  const size_t need = 48 * MB + NN * sizeof(float);
  if (ws_size < need) {
    fallback_gemm<<<dim3(NN / 16, MM / 16), dim3(16, 16), 0, stream>>>(x, E, W, cb, out);
    return;
  }

  char* ws = (char*)d_ws;
  unsigned short* Ahi = (unsigned short*)(ws);            // 16 MB
  unsigned short* Alo = (unsigned short*)(ws + 16 * MB);  // 16 MB
  unsigned short* Bhi = (unsigned short*)(ws + 32 * MB);  //  8 MB
  unsigned short* Blo = (unsigned short*)(ws + 40 * MB);  //  8 MB
  float* bias2 = (float*)(ws + 48 * MB);                  //  8 KB

  const int n4 = MM * KK / 4;
  split_x_kernel<<<dim3((n4 + 255) / 256), dim3(256), 0, stream>>>(x, Ahi, Alo, n4);
  wsplit_kernel<<<dim3(NN / 32, KK / 32), dim3(32, 8), 0, stream>>>(W, Bhi, Blo);
  bias_probs_kernel<<<dim3((NN + 255) / 256), dim3(256), 0, stream>>>(E, cb, bias2);
  gemm_tanh_kernel<<<dim3(NN / 128, MM / 128), dim3(256), 0, stream>>>(
      Ahi, Alo, Bhi, Blo, bias2, out);
}